// Round 6
// baseline (400.367 us; speedup 1.0000x reference)
//
#include <hip/hip_runtime.h>
#include <cstdint>
#include <cstddef>

// ---------------------------------------------------------------------------
// Attention_84155589198714: qkv = ctx @ W + b; causal softmax(q k^T / sqrt(N)); @ v
// B=4, N=2048, D=1024. All GEMMs in bf16 MFMA (16x16x32), fp32 accumulate.
// Softmax: scores bounded (|s| < ~8) -> no max subtraction; P=exp(s) unnorm,
// row sums via atomics, divide in PV epilogue.
//
// R2: XOR bank swizzle (conflicts -> 0, verified). 73.5 us gemm @ 88 VGPR.
// R4 lesson: fused epilogues -> LICM hoist -> VGPR 144, occupancy halved.
// R5: split gemms + relay pipeline for scores/pv. FAILED: relay prefetch
//   loaded into the wrong register set (write pushed stale tile0 at kt=1).
// R6: fix = load target is the OTHER set (odd ? rb : ra). Sequence:
//   pre: ra<-t0, rb<-t1, write ra. kt: write (odd?ra:rb)=t(kt+1),
//   load (odd?rb:ra)<-t(kt+2). Write source always loaded 2 phases earlier.
// ---------------------------------------------------------------------------

typedef __attribute__((ext_vector_type(8))) __bf16 bf16x8;
typedef __attribute__((ext_vector_type(4))) float f32x4;

__device__ inline unsigned short f2bf(float f) {
  unsigned u = __float_as_uint(f);
  u = (u + 0x7FFFu + ((u >> 16) & 1u)) >> 16;  // RNE
  return (unsigned short)u;
}

__device__ inline void gld16(const void* g, void* l) {
  __builtin_amdgcn_global_load_lds(
      (const __attribute__((address_space(1))) unsigned int*)g,
      (__attribute__((address_space(3))) unsigned int*)l, 16, 0, 0);
}

// Raw workgroup barrier: drain LDS ops only (NOT vmcnt), then s_barrier.
__device__ inline void raw_barrier_lds() {
  asm volatile("s_waitcnt lgkmcnt(0)\n\ts_barrier" ::: "memory");
}

// --------------------- shared tile-compute (swapped) -----------------------
// LDS layout per tile: row r (0..127) = 64 elems at r*64; 8-elem chunk c of
// row r stored at chunk position c ^ (r&7) (XOR bank swizzle).
// compute: output lane&15 = m (A row), 4 acc regs = 4 consecutive n (B row).
__device__ inline void compute_tiles(const unsigned short* As, const unsigned short* Bs,
                                     int lane, int ry, int rx, f32x4 acc[4][4]) {
#pragma unroll
  for (int kk = 0; kk < 64; kk += 32) {
    const int cbase = (kk >> 3) + (lane >> 4);          // chunk 0..7
    const int csw = ((cbase ^ (lane & 7)) << 3);        // swizzled elem offset
    bf16x8 a[4], b[4];
#pragma unroll
    for (int mi = 0; mi < 4; mi++)
      a[mi] = *(const bf16x8*)&As[(ry + mi * 16 + (lane & 15)) * 64 + csw];
#pragma unroll
    for (int nj = 0; nj < 4; nj++)
      b[nj] = *(const bf16x8*)&Bs[(rx + nj * 16 + (lane & 15)) * 64 + csw];
#pragma unroll
    for (int mi = 0; mi < 4; mi++)
#pragma unroll
      for (int nj = 0; nj < 4; nj++)
        acc[mi][nj] = __builtin_amdgcn_mfma_f32_16x16x32_bf16(b[nj], a[mi], acc[mi][nj], 0, 0, 0);
  }
}

// ------------------- single-buffered mainloop (gemms) ----------------------
__device__ inline void mma_mainloop(unsigned short* As, unsigned short* Bs,
                                    const unsigned short* Abase, long strideA,
                                    const unsigned short* Bbase, long strideB,
                                    int kIters, f32x4 acc[4][4]) {
  const int lane = threadIdx.x & 63, wave = threadIdx.x >> 6;
  const int ry = (wave >> 1) * 64, rx = (wave & 1) * 64;
  const int lrow = lane >> 3;
  const int lcol = ((lane & 7) ^ lrow) * 8;
#pragma unroll
  for (int mi = 0; mi < 4; mi++)
#pragma unroll
    for (int nj = 0; nj < 4; nj++) acc[mi][nj] = (f32x4)(0.f);
  for (int kt = 0; kt < kIters; kt++) {
    const int k0 = kt * 64;
    __syncthreads();
#pragma unroll
    for (int c = 0; c < 4; c++) {
      const int q = wave * 4 + c;
      const int row = q * 8 + lrow;
      gld16(Abase + (size_t)row * strideA + k0 + lcol, &As[q * 512]);
      gld16(Bbase + (size_t)row * strideB + k0 + lcol, &Bs[q * 512]);
    }
    __syncthreads();
    compute_tiles(As, Bs, lane, ry, rx, acc);
  }
}

// ------------------- relay mainloop (scores / pv) --------------------------
// Per thread: 8x uint4 per k-tile (A 4 chunks + B 4 chunks, 16 B each), same
// placement as gld16 (chunk q = wave*4+c, dest = q*1KB + lane*16B).
__device__ inline void relay_load(uint4 r[8],
                                  const unsigned short* Abase, long sA,
                                  const unsigned short* Bbase, long sB,
                                  int k0, int wave, int lrow, int lcol) {
#pragma unroll
  for (int c = 0; c < 4; c++) {
    const int row = (wave * 4 + c) * 8 + lrow;
    r[c]     = *(const uint4*)(Abase + (size_t)row * sA + k0 + lcol);
    r[4 + c] = *(const uint4*)(Bbase + (size_t)row * sB + k0 + lcol);
  }
}
__device__ inline void relay_write(const uint4 r[8], unsigned short* As,
                                   unsigned short* Bs, int wave, int lane) {
#pragma unroll
  for (int c = 0; c < 4; c++) {
    const int q = wave * 4 + c;
    *(uint4*)&As[q * 512 + lane * 8] = r[c];
    *(uint4*)&Bs[q * 512 + lane * 8] = r[4 + c];
  }
}

__device__ inline void mma_mainloop_relay(unsigned short* As0, unsigned short* Bs0,
                                          unsigned short* As1, unsigned short* Bs1,
                                          const unsigned short* Abase, long sA,
                                          const unsigned short* Bbase, long sB,
                                          int kIters, f32x4 acc[4][4]) {
  const int lane = threadIdx.x & 63, wave = threadIdx.x >> 6;
  const int ry = (wave >> 1) * 64, rx = (wave & 1) * 64;
  const int lrow = lane >> 3;
  const int lcol = ((lane & 7) ^ lrow) * 8;
#pragma unroll
  for (int mi = 0; mi < 4; mi++)
#pragma unroll
    for (int nj = 0; nj < 4; nj++) acc[mi][nj] = (f32x4)(0.f);

  uint4 ra[8], rb[8];
  relay_load(ra, Abase, sA, Bbase, sB, 0, wave, lrow, lcol);            // ra <- tile0
  if (kIters > 1) relay_load(rb, Abase, sA, Bbase, sB, 64, wave, lrow, lcol);  // rb <- tile1
  relay_write(ra, As0, Bs0, wave, lane);  // tile0 -> buf0 (waits vmcnt for ra only)
  raw_barrier_lds();                      // buf0 ready; rb loads still in flight

  for (int kt = 0; kt < kIters; kt++) {
    const bool odd = kt & 1;
    unsigned short* Asc = odd ? As1 : As0;
    unsigned short* Bsc = odd ? Bs1 : Bs0;
    if (kt + 1 < kIters) {
      unsigned short* Asn = odd ? As0 : As1;
      unsigned short* Bsn = odd ? Bs0 : Bs1;
      // barrier: all waves done computing iter kt-1 (which read buf[(kt+1)&1])
      raw_barrier_lds();
      relay_write(odd ? ra : rb, Asn, Bsn, wave, lane);  // tile kt+1 -> LDS
      if (kt + 2 < kIters)  // R6 FIX: refill the OTHER set (freed 2 phases ago)
        relay_load(odd ? rb : ra, Abase, sA, Bbase, sB, (kt + 2) * 64, wave, lrow, lcol);
      raw_barrier_lds();  // buf[(kt+1)&1] populated by all waves
    }
    compute_tiles(Asc, Bsc, lane, ry, rx, acc);
  }
}

// --------------------------- prep kernels ----------------------------------

__global__ void k_convert(const float* __restrict__ x, unsigned short* __restrict__ y, int n4) {
  int i = blockIdx.x * blockDim.x + threadIdx.x;
  if (i >= n4) return;
  float4 v = ((const float4*)x)[i];
  ushort4 o;
  o.x = f2bf(v.x); o.y = f2bf(v.y); o.z = f2bf(v.z); o.w = f2bf(v.w);
  ((ushort4*)y)[i] = o;
}

// W [1024][3072] fp32 -> Wt [3072][1024] bf16
__global__ void k_transpose_w(const float* __restrict__ W, unsigned short* __restrict__ Wt) {
  __shared__ unsigned short sm[64 * 65];
  const int n0 = blockIdx.x * 64;
  const int k0 = blockIdx.y * 64;
  for (int i = threadIdx.x; i < 4096; i += 256) {
    int r = i >> 6, c = i & 63;
    sm[c * 65 + r] = f2bf(W[(size_t)(k0 + r) * 3072 + n0 + c]);
  }
  __syncthreads();
  for (int i = threadIdx.x; i < 4096; i += 256) {
    int r = i >> 6, c = i & 63;
    Wt[(size_t)(n0 + r) * 1024 + k0 + c] = sm[r * 65 + c];
  }
}

// --------------------------- GEMM kernels ----------------------------------

// qk features: qk[m 8192][n 2048] = ctx @ Wt[n][k] + b, contiguous ushort4.
__global__ __launch_bounds__(256) void k_gemm_qk(const unsigned short* __restrict__ A,
                                                 const unsigned short* __restrict__ Wt,
                                                 const float* __restrict__ bias,
                                                 unsigned short* __restrict__ qk) {
  __shared__ unsigned short As[128 * 64];
  __shared__ unsigned short Bs[128 * 64];
  f32x4 acc[4][4];
  const int tN0 = blockIdx.x * 128;
  const int tM0 = blockIdx.y * 128;
  mma_mainloop(As, Bs, A + (size_t)tM0 * 1024, 1024, Wt + (size_t)tN0 * 1024, 1024, 16, acc);
  const int lane = threadIdx.x & 63, wave = threadIdx.x >> 6;
  const int ry = (wave >> 1) * 64, rx = (wave & 1) * 64;
  const int l16 = lane & 15, rq = lane >> 4;
#pragma unroll
  for (int mi = 0; mi < 4; mi++) {
    const int m = tM0 + ry + mi * 16 + l16;
#pragma unroll
    for (int nj = 0; nj < 4; nj++) {
      const int n = tN0 + rx + nj * 16 + rq * 4;
      const float4 bv = *(const float4*)&bias[n];
      ushort4 o;
      o.x = f2bf(acc[mi][nj][0] + bv.x);
      o.y = f2bf(acc[mi][nj][1] + bv.y);
      o.z = f2bf(acc[mi][nj][2] + bv.z);
      o.w = f2bf(acc[mi][nj][3] + bv.w);
      *(ushort4*)&qk[(size_t)m * 2048 + n] = o;
    }
  }
}

// v features -> vT[b][d][n] directly (swapped layout: lanes l16 = consecutive
// seq for each d => 32 B contiguous runs per quad). Anti-hoist barrier keeps
// the epilogue address math out of the K-loop's register budget.
__global__ __launch_bounds__(256) void k_gemm_v(const unsigned short* __restrict__ A,
                                                const unsigned short* __restrict__ Wt,
                                                const float* __restrict__ bias,
                                                unsigned short* __restrict__ vT) {
  __shared__ unsigned short As[128 * 64];
  __shared__ unsigned short Bs[128 * 64];
  f32x4 acc[4][4];
  const int tN0 = blockIdx.x * 128;  // v feature block
  const int tM0 = blockIdx.y * 128;
  mma_mainloop(As, Bs, A + (size_t)tM0 * 1024, 1024,
               Wt + (size_t)(2048 + tN0) * 1024, 1024, 16, acc);
  int tM0v = tM0;
  asm volatile("" : "+v"(tM0v));  // block LICM of epilogue addresses into loop
  const int lane = threadIdx.x & 63, wave = threadIdx.x >> 6;
  const int ry = (wave >> 1) * 64, rx = (wave & 1) * 64;
  const int l16 = lane & 15, rq = lane >> 4;
#pragma unroll
  for (int mi = 0; mi < 4; mi++) {
    const int m = tM0v + ry + mi * 16 + l16;  // global seq
    const int b = m >> 11, ns = m & 2047;
#pragma unroll
    for (int nj = 0; nj < 4; nj++) {
      const int d0 = tN0 + rx + nj * 16 + rq * 4;
      const float4 bv = *(const float4*)&bias[2048 + d0];
#pragma unroll
      for (int r = 0; r < 4; r++)
        vT[((size_t)(b * 1024 + d0 + r)) * 2048 + ns] =
            f2bf(acc[mi][nj][r] + ((const float*)&bv)[r]);
    }
  }
}

// P_unnorm tile + row-sum atomics. 1-D triangular grid over (qb,kb), z = batch.
__global__ __launch_bounds__(256) void k_scores(const unsigned short* __restrict__ qk,
                                                unsigned short* __restrict__ P,
                                                float* __restrict__ l, float scale) {
  __shared__ unsigned short As0[128 * 64], Bs0[128 * 64];
  __shared__ unsigned short As1[128 * 64], Bs1[128 * 64];
  const int t = blockIdx.x, b = blockIdx.z;
  int qb = (int)((sqrtf(8.0f * (float)t + 1.0f) - 1.0f) * 0.5f);
  while (qb * (qb + 1) / 2 > t) qb--;
  while ((qb + 1) * (qb + 2) / 2 <= t) qb++;
  const int kb = t - qb * (qb + 1) / 2;
  f32x4 acc[4][4];
  const unsigned short* Aq = qk + ((size_t)(b * 2048 + qb * 128)) * 2048;
  const unsigned short* Bk = qk + ((size_t)(b * 2048 + kb * 128)) * 2048 + 1024;
  mma_mainloop_relay(As0, Bs0, As1, Bs1, Aq, 2048, Bk, 2048, 16, acc);
  const int lane = threadIdx.x & 63, wave = threadIdx.x >> 6;
  const int ry = (wave >> 1) * 64, rx = (wave & 1) * 64;
  const int l16 = lane & 15, rq = lane >> 4;
  unsigned short* Pb = P + ((size_t)(b * 2048 + qb * 128)) * 2048 + (size_t)kb * 128;
  float* lb = l + b * 2048 + qb * 128;
#pragma unroll
  for (int mi = 0; mi < 4; mi++) {
    const int m_local = ry + mi * 16 + l16;
    const int qi = qb * 128 + m_local;
    float rowpart = 0.f;
#pragma unroll
    for (int nj = 0; nj < 4; nj++) {
      const int n_base = rx + nj * 16 + rq * 4;
      ushort4 o;
      float p;
#pragma unroll
      for (int r = 0; r < 4; r++) {
        const int kj = kb * 128 + n_base + r;
        p = (kj <= qi) ? __expf(acc[mi][nj][r] * scale) : 0.f;
        rowpart += p;
        ((unsigned short*)&o)[r] = f2bf(p);
      }
      *(ushort4*)&Pb[(size_t)m_local * 2048 + n_base] = o;
    }
    rowpart += __shfl_xor(rowpart, 16, 64);
    rowpart += __shfl_xor(rowpart, 32, 64);
    if (rq == 0) atomicAdd(&lb[m_local], rowpart);
  }
}

// out[m][d] = (P[m][:] @ vT[d][:]) / l[m].  grid (db, qb, b); causal k-range;
// qb flipped on half the batches so each CU pairs deep and shallow tiles.
__global__ __launch_bounds__(256) void k_pv(const unsigned short* __restrict__ P,
                                            const unsigned short* __restrict__ vT,
                                            const float* __restrict__ l,
                                            float* __restrict__ out) {
  __shared__ unsigned short As0[128 * 64], Bs0[128 * 64];
  __shared__ unsigned short As1[128 * 64], Bs1[128 * 64];
  const int db = blockIdx.x, b = blockIdx.z;
  int qb = blockIdx.y;
  if (b & 2) qb = 15 - qb;
  f32x4 acc[4][4];
  const unsigned short* Ap = P + ((size_t)(b * 2048 + qb * 128)) * 2048;
  const unsigned short* Bv = vT + ((size_t)(b * 1024 + db * 128)) * 2048;
  mma_mainloop_relay(As0, Bs0, As1, Bs1, Ap, 2048, Bv, 2048, (qb + 1) * 2, acc);
  const int lane = threadIdx.x & 63, wave = threadIdx.x >> 6;
  const int ry = (wave >> 1) * 64, rx = (wave & 1) * 64;
  const int l16 = lane & 15, rq = lane >> 4;
  const float* lb = l + b * 2048 + qb * 128;
  float* ob = out + ((size_t)(b * 2048 + qb * 128)) * 1024 + db * 128;
#pragma unroll
  for (int mi = 0; mi < 4; mi++) {
    const int m_local = ry + mi * 16 + l16;
    const float inv = 1.0f / lb[m_local];
#pragma unroll
    for (int nj = 0; nj < 4; nj++) {
      const int n_base = rx + nj * 16 + rq * 4;
      float4 o;
      o.x = acc[mi][nj][0] * inv;
      o.y = acc[mi][nj][1] * inv;
      o.z = acc[mi][nj][2] * inv;
      o.w = acc[mi][nj][3] * inv;
      *(float4*)&ob[(size_t)m_local * 1024 + n_base] = o;
    }
  }
}

// ---------------------------------------------------------------------------

extern "C" void kernel_launch(void* const* d_in, const int* in_sizes, int n_in,
                              void* d_out, int out_size, void* d_ws, size_t ws_size,
                              hipStream_t stream) {
  const float* ctx  = (const float*)d_in[0];  // [4,2048,1024]
  const float* W    = (const float*)d_in[1];  // [1024,3072]
  const float* bias = (const float*)d_in[2];  // [3072]
  float* out = (float*)d_out;

  char* ws = (char*)d_ws;
  unsigned short* Actx = (unsigned short*)(ws + 0);          // 16,777,216
  unsigned short* Wt   = (unsigned short*)(ws + 16777216);   //  6,291,456
  unsigned short* qk   = (unsigned short*)(ws + 23068672);   // 33,554,432
  unsigned short* vT   = (unsigned short*)(ws + 56623104);   // 16,777,216
  unsigned short* P    = (unsigned short*)(ws + 73400320);   // 33,554,432
  float*          lsum = (float*)(ws + 106954752);           //     32,768

  hipMemsetAsync(lsum, 0, 4 * 2048 * sizeof(float), stream);
  k_convert<<<8192, 256, 0, stream>>>(ctx, Actx, (8192 * 1024) / 4);
  k_transpose_w<<<dim3(48, 16), 256, 0, stream>>>(W, Wt);
  k_gemm_qk<<<dim3(16, 64), 256, 0, stream>>>(Actx, Wt, bias, qk);
  k_gemm_v<<<dim3(8, 64), 256, 0, stream>>>(Actx, Wt, bias, vT);
  k_scores<<<dim3(136, 1, 4), 256, 0, stream>>>(qk, P, lsum, 0.022097086912079608f);
  k_pv<<<dim3(8, 16, 4), 256, 0, stream>>>(P, vT, lsum, out);
}

// Round 7
// 399.694 us; speedup vs baseline: 1.0017x; 1.0017x over previous
//
#include <hip/hip_runtime.h>
#include <cstdint>
#include <cstddef>

// ---------------------------------------------------------------------------
// Attention_84155589198714: qkv = ctx @ W + b; causal softmax(q k^T / sqrt(N)); @ v
// B=4, N=2048, D=1024. All GEMMs in bf16 MFMA (16x16x32), fp32 accumulate.
// Softmax: scores bounded (|s| < ~8) -> no max subtraction; P=exp(s) unnorm,
// row sums via atomics, divide in PV epilogue.
//
// R2: XOR bank swizzle (conflicts -> 0). R4: fused epilogues hoisted -> VGPR
// 144 (lesson: keep one epilogue per kernel). R6 lesson: runtime-selected
// register arrays (odd ? ra : rb) forced ra/rb into SCRATCH -> 283 MB
// WRITE_SIZE, MfmaUtil 5%. R7: pipeline unrolled x2 with STATIC register
// roles (kIters always even here): even phase writes rb->buf1, refills ra;
// odd phase writes ra->buf0, refills rb. Raw lgkm-only barriers; global
// prefetches never drained at a barrier; prefetch distance 2.
// ---------------------------------------------------------------------------

typedef __attribute__((ext_vector_type(8))) __bf16 bf16x8;
typedef __attribute__((ext_vector_type(4))) float f32x4;

__device__ inline unsigned short f2bf(float f) {
  unsigned u = __float_as_uint(f);
  u = (u + 0x7FFFu + ((u >> 16) & 1u)) >> 16;  // RNE
  return (unsigned short)u;
}

__device__ inline void gld16(const void* g, void* l) {
  __builtin_amdgcn_global_load_lds(
      (const __attribute__((address_space(1))) unsigned int*)g,
      (__attribute__((address_space(3))) unsigned int*)l, 16, 0, 0);
}

// Raw workgroup barrier: drain LDS ops only (NOT vmcnt), then s_barrier.
__device__ inline void raw_barrier_lds() {
  asm volatile("s_waitcnt lgkmcnt(0)\n\ts_barrier" ::: "memory");
}

// --------------------- shared tile-compute (swapped) -----------------------
// LDS layout per tile: row r (0..127) = 64 elems at r*64; 8-elem chunk c of
// row r stored at chunk position c ^ (r&7) (XOR bank swizzle).
// compute: output lane&15 = m (A row), 4 acc regs = 4 consecutive n (B row).
__device__ inline void compute_tiles(const unsigned short* As, const unsigned short* Bs,
                                     int lane, int ry, int rx, f32x4 acc[4][4]) {
#pragma unroll
  for (int kk = 0; kk < 64; kk += 32) {
    const int cbase = (kk >> 3) + (lane >> 4);          // chunk 0..7
    const int csw = ((cbase ^ (lane & 7)) << 3);        // swizzled elem offset
    bf16x8 a[4], b[4];
#pragma unroll
    for (int mi = 0; mi < 4; mi++)
      a[mi] = *(const bf16x8*)&As[(ry + mi * 16 + (lane & 15)) * 64 + csw];
#pragma unroll
    for (int nj = 0; nj < 4; nj++)
      b[nj] = *(const bf16x8*)&Bs[(rx + nj * 16 + (lane & 15)) * 64 + csw];
#pragma unroll
    for (int mi = 0; mi < 4; mi++)
#pragma unroll
      for (int nj = 0; nj < 4; nj++)
        acc[mi][nj] = __builtin_amdgcn_mfma_f32_16x16x32_bf16(b[nj], a[mi], acc[mi][nj], 0, 0, 0);
  }
}

// ------------------- single-buffered mainloop (gemms) ----------------------
__device__ inline void mma_mainloop(unsigned short* As, unsigned short* Bs,
                                    const unsigned short* Abase, long strideA,
                                    const unsigned short* Bbase, long strideB,
                                    int kIters, f32x4 acc[4][4]) {
  const int lane = threadIdx.x & 63, wave = threadIdx.x >> 6;
  const int ry = (wave >> 1) * 64, rx = (wave & 1) * 64;
  const int lrow = lane >> 3;
  const int lcol = ((lane & 7) ^ lrow) * 8;
#pragma unroll
  for (int mi = 0; mi < 4; mi++)
#pragma unroll
    for (int nj = 0; nj < 4; nj++) acc[mi][nj] = (f32x4)(0.f);
  for (int kt = 0; kt < kIters; kt++) {
    const int k0 = kt * 64;
    __syncthreads();
#pragma unroll
    for (int c = 0; c < 4; c++) {
      const int q = wave * 4 + c;
      const int row = q * 8 + lrow;
      gld16(Abase + (size_t)row * strideA + k0 + lcol, &As[q * 512]);
      gld16(Bbase + (size_t)row * strideB + k0 + lcol, &Bs[q * 512]);
    }
    __syncthreads();
    compute_tiles(As, Bs, lane, ry, rx, acc);
  }
}

// ------------------- relay mainloop (scores / pv) --------------------------
// Per thread: 8x uint4 per k-tile (A 4 chunks + B 4 chunks, 16 B each), same
// placement as gld16 (chunk q = wave*4+c, dest = q*1KB + lane*16B).
// All array indexing is STATIC (R7) so ra/rb stay in VGPRs.
__device__ inline void relay_load(uint4 (&r)[8],
                                  const unsigned short* Abase, long sA,
                                  const unsigned short* Bbase, long sB,
                                  int k0, int wave, int lrow, int lcol) {
#pragma unroll
  for (int c = 0; c < 4; c++) {
    const int row = (wave * 4 + c) * 8 + lrow;
    r[c]     = *(const uint4*)(Abase + (size_t)row * sA + k0 + lcol);
    r[4 + c] = *(const uint4*)(Bbase + (size_t)row * sB + k0 + lcol);
  }
}
__device__ inline void relay_write(const uint4 (&r)[8], unsigned short* As,
                                   unsigned short* Bs, int wave, int lane) {
#pragma unroll
  for (int c = 0; c < 4; c++) {
    const int q = wave * 4 + c;
    *(uint4*)&As[q * 512 + lane * 8] = r[c];
    *(uint4*)&Bs[q * 512 + lane * 8] = r[4 + c];
  }
}

// REQUIRES kIters even and >= 2 (scores: 16, pv: (qb+1)*2).
__device__ inline void mma_mainloop_relay(unsigned short* As0, unsigned short* Bs0,
                                          unsigned short* As1, unsigned short* Bs1,
                                          const unsigned short* Abase, long sA,
                                          const unsigned short* Bbase, long sB,
                                          int kIters, f32x4 acc[4][4]) {
  const int lane = threadIdx.x & 63, wave = threadIdx.x >> 6;
  const int ry = (wave >> 1) * 64, rx = (wave & 1) * 64;
  const int lrow = lane >> 3;
  const int lcol = ((lane & 7) ^ lrow) * 8;
#pragma unroll
  for (int mi = 0; mi < 4; mi++)
#pragma unroll
    for (int nj = 0; nj < 4; nj++) acc[mi][nj] = (f32x4)(0.f);

  uint4 ra[8], rb[8];
  relay_load(ra, Abase, sA, Bbase, sB, 0, wave, lrow, lcol);    // ra <- t0
  relay_load(rb, Abase, sA, Bbase, sB, 64, wave, lrow, lcol);   // rb <- t1
  relay_write(ra, As0, Bs0, wave, lane);  // t0 -> buf0 (vmcnt waits ra only)
  raw_barrier_lds();                      // buf0 ready; rb still in flight

  // Loop invariant at pair top: buf0 = tile kt, rb = tile kt+1, ra free.
  for (int kt = 0; kt < kIters; kt += 2) {
    // even phase: stage t(kt+1) -> buf1, refill ra <- t(kt+2), compute buf0
    raw_barrier_lds();                       // waves done reading buf1 (kt-1)
    relay_write(rb, As1, Bs1, wave, lane);   // t(kt+1) -> buf1
    if (kt + 2 < kIters)
      relay_load(ra, Abase, sA, Bbase, sB, (kt + 2) * 64, wave, lrow, lcol);
    raw_barrier_lds();                       // buf1 populated by all waves
    compute_tiles(As0, Bs0, lane, ry, rx, acc);   // tile kt

    // odd phase: stage t(kt+2) -> buf0, refill rb <- t(kt+3), compute buf1
    if (kt + 2 < kIters) {
      raw_barrier_lds();                     // waves done reading buf0 (even)
      relay_write(ra, As0, Bs0, wave, lane); // t(kt+2) -> buf0
      if (kt + 3 < kIters)
        relay_load(rb, Abase, sA, Bbase, sB, (kt + 3) * 64, wave, lrow, lcol);
      raw_barrier_lds();                     // buf0 populated
    }
    compute_tiles(As1, Bs1, lane, ry, rx, acc);   // tile kt+1
  }
}

// --------------------------- prep kernels ----------------------------------

__global__ void k_convert(const float* __restrict__ x, unsigned short* __restrict__ y, int n4) {
  int i = blockIdx.x * blockDim.x + threadIdx.x;
  if (i >= n4) return;
  float4 v = ((const float4*)x)[i];
  ushort4 o;
  o.x = f2bf(v.x); o.y = f2bf(v.y); o.z = f2bf(v.z); o.w = f2bf(v.w);
  ((ushort4*)y)[i] = o;
}

// W [1024][3072] fp32 -> Wt [3072][1024] bf16
__global__ void k_transpose_w(const float* __restrict__ W, unsigned short* __restrict__ Wt) {
  __shared__ unsigned short sm[64 * 65];
  const int n0 = blockIdx.x * 64;
  const int k0 = blockIdx.y * 64;
  for (int i = threadIdx.x; i < 4096; i += 256) {
    int r = i >> 6, c = i & 63;
    sm[c * 65 + r] = f2bf(W[(size_t)(k0 + r) * 3072 + n0 + c]);
  }
  __syncthreads();
  for (int i = threadIdx.x; i < 4096; i += 256) {
    int r = i >> 6, c = i & 63;
    Wt[(size_t)(n0 + r) * 1024 + k0 + c] = sm[r * 65 + c];
  }
}

// --------------------------- GEMM kernels ----------------------------------

// qk features: qk[m 8192][n 2048] = ctx @ Wt[n][k] + b, contiguous ushort4.
__global__ __launch_bounds__(256) void k_gemm_qk(const unsigned short* __restrict__ A,
                                                 const unsigned short* __restrict__ Wt,
                                                 const float* __restrict__ bias,
                                                 unsigned short* __restrict__ qk) {
  __shared__ unsigned short As[128 * 64];
  __shared__ unsigned short Bs[128 * 64];
  f32x4 acc[4][4];
  const int tN0 = blockIdx.x * 128;
  const int tM0 = blockIdx.y * 128;
  mma_mainloop(As, Bs, A + (size_t)tM0 * 1024, 1024, Wt + (size_t)tN0 * 1024, 1024, 16, acc);
  const int lane = threadIdx.x & 63, wave = threadIdx.x >> 6;
  const int ry = (wave >> 1) * 64, rx = (wave & 1) * 64;
  const int l16 = lane & 15, rq = lane >> 4;
#pragma unroll
  for (int mi = 0; mi < 4; mi++) {
    const int m = tM0 + ry + mi * 16 + l16;
#pragma unroll
    for (int nj = 0; nj < 4; nj++) {
      const int n = tN0 + rx + nj * 16 + rq * 4;
      const float4 bv = *(const float4*)&bias[n];
      ushort4 o;
      o.x = f2bf(acc[mi][nj][0] + bv.x);
      o.y = f2bf(acc[mi][nj][1] + bv.y);
      o.z = f2bf(acc[mi][nj][2] + bv.z);
      o.w = f2bf(acc[mi][nj][3] + bv.w);
      *(ushort4*)&qk[(size_t)m * 2048 + n] = o;
    }
  }
}

// v features -> vT[b][d][n] directly (swapped layout: lanes l16 = consecutive
// seq for each d => 32 B contiguous runs per quad). Anti-hoist barrier keeps
// the epilogue address math out of the K-loop's register budget.
__global__ __launch_bounds__(256) void k_gemm_v(const unsigned short* __restrict__ A,
                                                const unsigned short* __restrict__ Wt,
                                                const float* __restrict__ bias,
                                                unsigned short* __restrict__ vT) {
  __shared__ unsigned short As[128 * 64];
  __shared__ unsigned short Bs[128 * 64];
  f32x4 acc[4][4];
  const int tN0 = blockIdx.x * 128;  // v feature block
  const int tM0 = blockIdx.y * 128;
  mma_mainloop(As, Bs, A + (size_t)tM0 * 1024, 1024,
               Wt + (size_t)(2048 + tN0) * 1024, 1024, 16, acc);
  int tM0v = tM0;
  asm volatile("" : "+v"(tM0v));  // block LICM of epilogue addresses into loop
  const int lane = threadIdx.x & 63, wave = threadIdx.x >> 6;
  const int ry = (wave >> 1) * 64, rx = (wave & 1) * 64;
  const int l16 = lane & 15, rq = lane >> 4;
#pragma unroll
  for (int mi = 0; mi < 4; mi++) {
    const int m = tM0v + ry + mi * 16 + l16;  // global seq
    const int b = m >> 11, ns = m & 2047;
#pragma unroll
    for (int nj = 0; nj < 4; nj++) {
      const int d0 = tN0 + rx + nj * 16 + rq * 4;
      const float4 bv = *(const float4*)&bias[2048 + d0];
#pragma unroll
      for (int r = 0; r < 4; r++)
        vT[((size_t)(b * 1024 + d0 + r)) * 2048 + ns] =
            f2bf(acc[mi][nj][r] + ((const float*)&bv)[r]);
    }
  }
}

// P_unnorm tile + row-sum atomics. 1-D triangular grid over (qb,kb), z = batch.
__global__ __launch_bounds__(256) void k_scores(const unsigned short* __restrict__ qk,
                                                unsigned short* __restrict__ P,
                                                float* __restrict__ l, float scale) {
  __shared__ unsigned short As0[128 * 64], Bs0[128 * 64];
  __shared__ unsigned short As1[128 * 64], Bs1[128 * 64];
  const int t = blockIdx.x, b = blockIdx.z;
  int qb = (int)((sqrtf(8.0f * (float)t + 1.0f) - 1.0f) * 0.5f);
  while (qb * (qb + 1) / 2 > t) qb--;
  while ((qb + 1) * (qb + 2) / 2 <= t) qb++;
  const int kb = t - qb * (qb + 1) / 2;
  f32x4 acc[4][4];
  const unsigned short* Aq = qk + ((size_t)(b * 2048 + qb * 128)) * 2048;
  const unsigned short* Bk = qk + ((size_t)(b * 2048 + kb * 128)) * 2048 + 1024;
  mma_mainloop_relay(As0, Bs0, As1, Bs1, Aq, 2048, Bk, 2048, 16, acc);
  const int lane = threadIdx.x & 63, wave = threadIdx.x >> 6;
  const int ry = (wave >> 1) * 64, rx = (wave & 1) * 64;
  const int l16 = lane & 15, rq = lane >> 4;
  unsigned short* Pb = P + ((size_t)(b * 2048 + qb * 128)) * 2048 + (size_t)kb * 128;
  float* lb = l + b * 2048 + qb * 128;
#pragma unroll
  for (int mi = 0; mi < 4; mi++) {
    const int m_local = ry + mi * 16 + l16;
    const int qi = qb * 128 + m_local;
    float rowpart = 0.f;
#pragma unroll
    for (int nj = 0; nj < 4; nj++) {
      const int n_base = rx + nj * 16 + rq * 4;
      ushort4 o;
      float p;
#pragma unroll
      for (int r = 0; r < 4; r++) {
        const int kj = kb * 128 + n_base + r;
        p = (kj <= qi) ? __expf(acc[mi][nj][r] * scale) : 0.f;
        rowpart += p;
        ((unsigned short*)&o)[r] = f2bf(p);
      }
      *(ushort4*)&Pb[(size_t)m_local * 2048 + n_base] = o;
    }
    rowpart += __shfl_xor(rowpart, 16, 64);
    rowpart += __shfl_xor(rowpart, 32, 64);
    if (rq == 0) atomicAdd(&lb[m_local], rowpart);
  }
}

// out[m][d] = (P[m][:] @ vT[d][:]) / l[m].  grid (db, qb, b); causal k-range;
// qb flipped on half the batches so each CU pairs deep and shallow tiles.
__global__ __launch_bounds__(256) void k_pv(const unsigned short* __restrict__ P,
                                            const unsigned short* __restrict__ vT,
                                            const float* __restrict__ l,
                                            float* __restrict__ out) {
  __shared__ unsigned short As0[128 * 64], Bs0[128 * 64];
  __shared__ unsigned short As1[128 * 64], Bs1[128 * 64];
  const int db = blockIdx.x, b = blockIdx.z;
  int qb = blockIdx.y;
  if (b & 2) qb = 15 - qb;
  f32x4 acc[4][4];
  const unsigned short* Ap = P + ((size_t)(b * 2048 + qb * 128)) * 2048;
  const unsigned short* Bv = vT + ((size_t)(b * 1024 + db * 128)) * 2048;
  mma_mainloop_relay(As0, Bs0, As1, Bs1, Ap, 2048, Bv, 2048, (qb + 1) * 2, acc);
  const int lane = threadIdx.x & 63, wave = threadIdx.x >> 6;
  const int ry = (wave >> 1) * 64, rx = (wave & 1) * 64;
  const int l16 = lane & 15, rq = lane >> 4;
  const float* lb = l + b * 2048 + qb * 128;
  float* ob = out + ((size_t)(b * 2048 + qb * 128)) * 1024 + db * 128;
#pragma unroll
  for (int mi = 0; mi < 4; mi++) {
    const int m_local = ry + mi * 16 + l16;
    const float inv = 1.0f / lb[m_local];
#pragma unroll
    for (int nj = 0; nj < 4; nj++) {
      const int n_base = rx + nj * 16 + rq * 4;
      float4 o;
      o.x = acc[mi][nj][0] * inv;
      o.y = acc[mi][nj][1] * inv;
      o.z = acc[mi][nj][2] * inv;
      o.w = acc[mi][nj][3] * inv;
      *(float4*)&ob[(size_t)m_local * 1024 + n_base] = o;
    }
  }
}

// ---------------------------------------------------------------------------

extern "C" void kernel_launch(void* const* d_in, const int* in_sizes, int n_in,
                              void* d_out, int out_size, void* d_ws, size_t ws_size,
                              hipStream_t stream) {
  const float* ctx  = (const float*)d_in[0];  // [4,2048,1024]
  const float* W    = (const float*)d_in[1];  // [1024,3072]
  const float* bias = (const float*)d_in[2];  // [3072]
  float* out = (float*)d_out;

  char* ws = (char*)d_ws;
  unsigned short* Actx = (unsigned short*)(ws + 0);          // 16,777,216
  unsigned short* Wt   = (unsigned short*)(ws + 16777216);   //  6,291,456
  unsigned short* qk   = (unsigned short*)(ws + 23068672);   // 33,554,432
  unsigned short* vT   = (unsigned short*)(ws + 56623104);   // 16,777,216
  unsigned short* P    = (unsigned short*)(ws + 73400320);   // 33,554,432
  float*          lsum = (float*)(ws + 106954752);           //     32,768

  hipMemsetAsync(lsum, 0, 4 * 2048 * sizeof(float), stream);
  k_convert<<<8192, 256, 0, stream>>>(ctx, Actx, (8192 * 1024) / 4);
  k_transpose_w<<<dim3(48, 16), 256, 0, stream>>>(W, Wt);
  k_gemm_qk<<<dim3(16, 64), 256, 0, stream>>>(Actx, Wt, bias, qk);
  k_gemm_v<<<dim3(8, 64), 256, 0, stream>>>(Actx, Wt, bias, vT);
  k_scores<<<dim3(136, 1, 4), 256, 0, stream>>>(qk, P, lsum, 0.022097086912079608f);
  k_pv<<<dim3(8, 16, 4), 256, 0, stream>>>(P, vT, lsum, out);
}

// Round 8
// 241.442 us; speedup vs baseline: 1.6582x; 1.6554x over previous
//
#include <hip/hip_runtime.h>
#include <cstdint>
#include <cstddef>

// ---------------------------------------------------------------------------
// Attention_84155589198714: qkv = ctx @ W + b; causal softmax(q k^T / sqrt(N)); @ v
// B=4, N=2048, D=1024. All GEMMs in bf16 MFMA (16x16x32), fp32 accumulate.
// Softmax: scores bounded (|s| < ~8) -> no max subtraction; P=exp(s) unnorm,
// row sums via atomics, divide in PV epilogue.
//
// R2: XOR bank swizzle (conflicts -> 0); gld16 mainloop = 700 TF at 6 blk/CU.
// R4: fused epilogues -> LICM VGPR blowup (keep one epilogue per kernel).
// R6/R7: VGPR-relay staging spills to scratch no matter what (283 MB scratch
//   traffic, MfmaUtil 5%) -- abandoned.
// R8: scores/pv keep the PROVEN gld16 single-buffer mainloop but with 128x64
//   tiles -> 1088/1024 blocks (~4 blocks/CU vs 2): occupancy, not loop
//   structure, was what made 128x128 scores/pv 3.4x less efficient than the
//   gemm. LDS 24 KB/block, acc 4x2 (32 VGPR).
// ---------------------------------------------------------------------------

typedef __attribute__((ext_vector_type(8))) __bf16 bf16x8;
typedef __attribute__((ext_vector_type(4))) float f32x4;

__device__ inline unsigned short f2bf(float f) {
  unsigned u = __float_as_uint(f);
  u = (u + 0x7FFFu + ((u >> 16) & 1u)) >> 16;  // RNE
  return (unsigned short)u;
}

__device__ inline void gld16(const void* g, void* l) {
  __builtin_amdgcn_global_load_lds(
      (const __attribute__((address_space(1))) unsigned int*)g,
      (__attribute__((address_space(3))) unsigned int*)l, 16, 0, 0);
}

// --------------------- 128x128 tile machinery (gemms) ----------------------
// LDS layout per tile: row r = 64 elems at r*64; 8-elem chunk c of row r at
// chunk position c ^ (r&7) (XOR bank swizzle). Swapped-operand MFMA:
// output lane&15 = m (A row), 4 acc regs = 4 consecutive n (B row).
__device__ inline void compute_tiles(const unsigned short* As, const unsigned short* Bs,
                                     int lane, int ry, int rx, f32x4 acc[4][4]) {
#pragma unroll
  for (int kk = 0; kk < 64; kk += 32) {
    const int cbase = (kk >> 3) + (lane >> 4);
    const int csw = ((cbase ^ (lane & 7)) << 3);
    bf16x8 a[4], b[4];
#pragma unroll
    for (int mi = 0; mi < 4; mi++)
      a[mi] = *(const bf16x8*)&As[(ry + mi * 16 + (lane & 15)) * 64 + csw];
#pragma unroll
    for (int nj = 0; nj < 4; nj++)
      b[nj] = *(const bf16x8*)&Bs[(rx + nj * 16 + (lane & 15)) * 64 + csw];
#pragma unroll
    for (int mi = 0; mi < 4; mi++)
#pragma unroll
      for (int nj = 0; nj < 4; nj++)
        acc[mi][nj] = __builtin_amdgcn_mfma_f32_16x16x32_bf16(b[nj], a[mi], acc[mi][nj], 0, 0, 0);
  }
}

__device__ inline void mma_mainloop(unsigned short* As, unsigned short* Bs,
                                    const unsigned short* Abase, long strideA,
                                    const unsigned short* Bbase, long strideB,
                                    int kIters, f32x4 acc[4][4]) {
  const int lane = threadIdx.x & 63, wave = threadIdx.x >> 6;
  const int ry = (wave >> 1) * 64, rx = (wave & 1) * 64;
  const int lrow = lane >> 3;
  const int lcol = ((lane & 7) ^ lrow) * 8;
#pragma unroll
  for (int mi = 0; mi < 4; mi++)
#pragma unroll
    for (int nj = 0; nj < 4; nj++) acc[mi][nj] = (f32x4)(0.f);
  for (int kt = 0; kt < kIters; kt++) {
    const int k0 = kt * 64;
    __syncthreads();
#pragma unroll
    for (int c = 0; c < 4; c++) {
      const int q = wave * 4 + c;
      const int row = q * 8 + lrow;
      gld16(Abase + (size_t)row * strideA + k0 + lcol, &As[q * 512]);
      gld16(Bbase + (size_t)row * strideB + k0 + lcol, &Bs[q * 512]);
    }
    __syncthreads();
    compute_tiles(As, Bs, lane, ry, rx, acc);
  }
}

// --------------------- 128x64 tile machinery (scores/pv) -------------------
// M=128 (A rows), N=64 (B rows). 4 waves in 2x2; wave-tile 64x32.
// acc[4][2]: mi over 4x16 rows, nj over 2x16 cols.
__device__ inline void compute_tiles64(const unsigned short* As, const unsigned short* Bs,
                                       int lane, int ry, int rx, f32x4 acc[4][2]) {
#pragma unroll
  for (int kk = 0; kk < 64; kk += 32) {
    const int cbase = (kk >> 3) + (lane >> 4);
    const int csw = ((cbase ^ (lane & 7)) << 3);
    bf16x8 a[4], b[2];
#pragma unroll
    for (int mi = 0; mi < 4; mi++)
      a[mi] = *(const bf16x8*)&As[(ry + mi * 16 + (lane & 15)) * 64 + csw];
#pragma unroll
    for (int nj = 0; nj < 2; nj++)
      b[nj] = *(const bf16x8*)&Bs[(rx + nj * 16 + (lane & 15)) * 64 + csw];
#pragma unroll
    for (int mi = 0; mi < 4; mi++)
#pragma unroll
      for (int nj = 0; nj < 2; nj++)
        acc[mi][nj] = __builtin_amdgcn_mfma_f32_16x16x32_bf16(b[nj], a[mi], acc[mi][nj], 0, 0, 0);
  }
}

__device__ inline void mma_mainloop64(unsigned short* As, unsigned short* Bs,
                                      const unsigned short* Abase, long strideA,
                                      const unsigned short* Bbase, long strideB,
                                      int kIters, f32x4 acc[4][2]) {
  const int lane = threadIdx.x & 63, wave = threadIdx.x >> 6;
  const int ry = (wave >> 1) * 64, rx = (wave & 1) * 32;
  const int lrow = lane >> 3;
  const int lcol = ((lane & 7) ^ lrow) * 8;
#pragma unroll
  for (int mi = 0; mi < 4; mi++)
#pragma unroll
    for (int nj = 0; nj < 2; nj++) acc[mi][nj] = (f32x4)(0.f);
  for (int kt = 0; kt < kIters; kt++) {
    const int k0 = kt * 64;
    __syncthreads();
#pragma unroll
    for (int c = 0; c < 4; c++) {  // A: 16 chunks of 8 rows -> 4 per wave
      const int q = wave * 4 + c;
      const int row = q * 8 + lrow;
      gld16(Abase + (size_t)row * strideA + k0 + lcol, &As[q * 512]);
    }
#pragma unroll
    for (int c = 0; c < 2; c++) {  // B: 8 chunks -> 2 per wave
      const int q = wave * 2 + c;
      const int row = q * 8 + lrow;
      gld16(Bbase + (size_t)row * strideB + k0 + lcol, &Bs[q * 512]);
    }
    __syncthreads();
    compute_tiles64(As, Bs, lane, ry, rx, acc);
  }
}

// --------------------------- prep kernels ----------------------------------

__global__ void k_convert(const float* __restrict__ x, unsigned short* __restrict__ y, int n4) {
  int i = blockIdx.x * blockDim.x + threadIdx.x;
  if (i >= n4) return;
  float4 v = ((const float4*)x)[i];
  ushort4 o;
  o.x = f2bf(v.x); o.y = f2bf(v.y); o.z = f2bf(v.z); o.w = f2bf(v.w);
  ((ushort4*)y)[i] = o;
}

// W [1024][3072] fp32 -> Wt [3072][1024] bf16
__global__ void k_transpose_w(const float* __restrict__ W, unsigned short* __restrict__ Wt) {
  __shared__ unsigned short sm[64 * 65];
  const int n0 = blockIdx.x * 64;
  const int k0 = blockIdx.y * 64;
  for (int i = threadIdx.x; i < 4096; i += 256) {
    int r = i >> 6, c = i & 63;
    sm[c * 65 + r] = f2bf(W[(size_t)(k0 + r) * 3072 + n0 + c]);
  }
  __syncthreads();
  for (int i = threadIdx.x; i < 4096; i += 256) {
    int r = i >> 6, c = i & 63;
    Wt[(size_t)(n0 + r) * 1024 + k0 + c] = sm[r * 65 + c];
  }
}

// --------------------------- GEMM kernels ----------------------------------

// qk features: qk[m 8192][n 2048] = ctx @ Wt[n][k] + b, contiguous ushort4.
__global__ __launch_bounds__(256) void k_gemm_qk(const unsigned short* __restrict__ A,
                                                 const unsigned short* __restrict__ Wt,
                                                 const float* __restrict__ bias,
                                                 unsigned short* __restrict__ qk) {
  __shared__ unsigned short As[128 * 64];
  __shared__ unsigned short Bs[128 * 64];
  f32x4 acc[4][4];
  const int tN0 = blockIdx.x * 128;
  const int tM0 = blockIdx.y * 128;
  mma_mainloop(As, Bs, A + (size_t)tM0 * 1024, 1024, Wt + (size_t)tN0 * 1024, 1024, 16, acc);
  const int lane = threadIdx.x & 63, wave = threadIdx.x >> 6;
  const int ry = (wave >> 1) * 64, rx = (wave & 1) * 64;
  const int l16 = lane & 15, rq = lane >> 4;
#pragma unroll
  for (int mi = 0; mi < 4; mi++) {
    const int m = tM0 + ry + mi * 16 + l16;
#pragma unroll
    for (int nj = 0; nj < 4; nj++) {
      const int n = tN0 + rx + nj * 16 + rq * 4;
      const float4 bv = *(const float4*)&bias[n];
      ushort4 o;
      o.x = f2bf(acc[mi][nj][0] + bv.x);
      o.y = f2bf(acc[mi][nj][1] + bv.y);
      o.z = f2bf(acc[mi][nj][2] + bv.z);
      o.w = f2bf(acc[mi][nj][3] + bv.w);
      *(ushort4*)&qk[(size_t)m * 2048 + n] = o;
    }
  }
}

// v features -> vT[b][d][n] directly (swapped layout: lanes l16 = consecutive
// seq for each d => 32 B contiguous runs per quad). Anti-hoist barrier keeps
// the epilogue address math out of the K-loop's register budget.
__global__ __launch_bounds__(256) void k_gemm_v(const unsigned short* __restrict__ A,
                                                const unsigned short* __restrict__ Wt,
                                                const float* __restrict__ bias,
                                                unsigned short* __restrict__ vT) {
  __shared__ unsigned short As[128 * 64];
  __shared__ unsigned short Bs[128 * 64];
  f32x4 acc[4][4];
  const int tN0 = blockIdx.x * 128;  // v feature block
  const int tM0 = blockIdx.y * 128;
  mma_mainloop(As, Bs, A + (size_t)tM0 * 1024, 1024,
               Wt + (size_t)(2048 + tN0) * 1024, 1024, 16, acc);
  int tM0v = tM0;
  asm volatile("" : "+v"(tM0v));  // block LICM of epilogue addresses into loop
  const int lane = threadIdx.x & 63, wave = threadIdx.x >> 6;
  const int ry = (wave >> 1) * 64, rx = (wave & 1) * 64;
  const int l16 = lane & 15, rq = lane >> 4;
#pragma unroll
  for (int mi = 0; mi < 4; mi++) {
    const int m = tM0v + ry + mi * 16 + l16;  // global seq
    const int b = m >> 11, ns = m & 2047;
#pragma unroll
    for (int nj = 0; nj < 4; nj++) {
      const int d0 = tN0 + rx + nj * 16 + rq * 4;
      const float4 bv = *(const float4*)&bias[2048 + d0];
#pragma unroll
      for (int r = 0; r < 4; r++)
        vT[((size_t)(b * 1024 + d0 + r)) * 2048 + ns] =
            f2bf(acc[mi][nj][r] + ((const float*)&bv)[r]);
    }
  }
}

// P_unnorm 128x64 tile + row-sum atomics. Triangular 1-D grid over
// (qb in 16, kb2 in 2qb+2), z = batch. 272 tiles/batch.
__global__ __launch_bounds__(256) void k_scores(const unsigned short* __restrict__ qk,
                                                unsigned short* __restrict__ P,
                                                float* __restrict__ l, float scale) {
  __shared__ unsigned short As[128 * 64];
  __shared__ unsigned short Bs[64 * 64];
  const int t = blockIdx.x, b = blockIdx.z;
  int qb = (int)((sqrtf(4.0f * (float)t + 1.0f) - 1.0f) * 0.5f);  // qb^2+qb <= t
  while (qb * (qb + 1) > t) qb--;
  while ((qb + 1) * (qb + 2) <= t) qb++;
  const int kb2 = t - qb * (qb + 1);  // 64-wide k tile, 0..2qb+1
  f32x4 acc[4][2];
  const unsigned short* Aq = qk + ((size_t)(b * 2048 + qb * 128)) * 2048;
  const unsigned short* Bk = qk + ((size_t)(b * 2048 + kb2 * 64)) * 2048 + 1024;
  mma_mainloop64(As, Bs, Aq, 2048, Bk, 2048, 16, acc);
  const int lane = threadIdx.x & 63, wave = threadIdx.x >> 6;
  const int ry = (wave >> 1) * 64, rx = (wave & 1) * 32;
  const int l16 = lane & 15, rq = lane >> 4;
  unsigned short* Pb = P + ((size_t)(b * 2048 + qb * 128)) * 2048 + (size_t)kb2 * 64;
  float* lb = l + b * 2048 + qb * 128;
#pragma unroll
  for (int mi = 0; mi < 4; mi++) {
    const int m_local = ry + mi * 16 + l16;
    const int qi = qb * 128 + m_local;
    float rowpart = 0.f;
#pragma unroll
    for (int nj = 0; nj < 2; nj++) {
      const int n_base = rx + nj * 16 + rq * 4;
      ushort4 o;
      float p;
#pragma unroll
      for (int r = 0; r < 4; r++) {
        const int kj = kb2 * 64 + n_base + r;
        p = (kj <= qi) ? __expf(acc[mi][nj][r] * scale) : 0.f;
        rowpart += p;
        ((unsigned short*)&o)[r] = f2bf(p);
      }
      *(ushort4*)&Pb[(size_t)m_local * 2048 + n_base] = o;
    }
    rowpart += __shfl_xor(rowpart, 16, 64);
    rowpart += __shfl_xor(rowpart, 32, 64);
    if (rq == 0) atomicAdd(&lb[m_local], rowpart);
  }
}

// out[m][d] = (P[m][:] @ vT[d][:]) / l[m].  128x64 tiles: grid (db2 16, qb 16,
// b 4); causal k-range (qb+1)*2 chunks; qb flipped on half the batches.
__global__ __launch_bounds__(256) void k_pv(const unsigned short* __restrict__ P,
                                            const unsigned short* __restrict__ vT,
                                            const float* __restrict__ l,
                                            float* __restrict__ out) {
  __shared__ unsigned short As[128 * 64];
  __shared__ unsigned short Bs[64 * 64];
  const int db2 = blockIdx.x, b = blockIdx.z;
  int qb = blockIdx.y;
  if (b & 2) qb = 15 - qb;  // balance causal depth across CUs
  f32x4 acc[4][2];
  const unsigned short* Ap = P + ((size_t)(b * 2048 + qb * 128)) * 2048;
  const unsigned short* Bv = vT + ((size_t)(b * 1024 + db2 * 64)) * 2048;
  mma_mainloop64(As, Bs, Ap, 2048, Bv, 2048, (qb + 1) * 2, acc);
  const int lane = threadIdx.x & 63, wave = threadIdx.x >> 6;
  const int ry = (wave >> 1) * 64, rx = (wave & 1) * 32;
  const int l16 = lane & 15, rq = lane >> 4;
  const float* lb = l + b * 2048 + qb * 128;
  float* ob = out + ((size_t)(b * 2048 + qb * 128)) * 1024 + db2 * 64;
#pragma unroll
  for (int mi = 0; mi < 4; mi++) {
    const int m_local = ry + mi * 16 + l16;
    const float inv = 1.0f / lb[m_local];
#pragma unroll
    for (int nj = 0; nj < 2; nj++) {
      const int n_base = rx + nj * 16 + rq * 4;
      float4 o;
      o.x = acc[mi][nj][0] * inv;
      o.y = acc[mi][nj][1] * inv;
      o.z = acc[mi][nj][2] * inv;
      o.w = acc[mi][nj][3] * inv;
      *(float4*)&ob[(size_t)m_local * 1024 + n_base] = o;
    }
  }
}

// ---------------------------------------------------------------------------

extern "C" void kernel_launch(void* const* d_in, const int* in_sizes, int n_in,
                              void* d_out, int out_size, void* d_ws, size_t ws_size,
                              hipStream_t stream) {
  const float* ctx  = (const float*)d_in[0];  // [4,2048,1024]
  const float* W    = (const float*)d_in[1];  // [1024,3072]
  const float* bias = (const float*)d_in[2];  // [3072]
  float* out = (float*)d_out;

  char* ws = (char*)d_ws;
  unsigned short* Actx = (unsigned short*)(ws + 0);          // 16,777,216
  unsigned short* Wt   = (unsigned short*)(ws + 16777216);   //  6,291,456
  unsigned short* qk   = (unsigned short*)(ws + 23068672);   // 33,554,432
  unsigned short* vT   = (unsigned short*)(ws + 56623104);   // 16,777,216
  unsigned short* P    = (unsigned short*)(ws + 73400320);   // 33,554,432
  float*          lsum = (float*)(ws + 106954752);           //     32,768

  hipMemsetAsync(lsum, 0, 4 * 2048 * sizeof(float), stream);
  k_convert<<<8192, 256, 0, stream>>>(ctx, Actx, (8192 * 1024) / 4);
  k_transpose_w<<<dim3(48, 16), 256, 0, stream>>>(W, Wt);
  k_gemm_qk<<<dim3(16, 64), 256, 0, stream>>>(Actx, Wt, bias, qk);
  k_gemm_v<<<dim3(8, 64), 256, 0, stream>>>(Actx, Wt, bias, vT);
  k_scores<<<dim3(272, 1, 4), 256, 0, stream>>>(qk, P, lsum, 0.022097086912079608f);
  k_pv<<<dim3(16, 16, 4), 256, 0, stream>>>(P, vT, lsum, out);
}